// Round 8
// baseline (178.374 us; speedup 1.0000x reference)
//
#include <hip/hip_runtime.h>

#define DD 256
#define HH 512
#define BB 128
#define TS 4096   // floats per tape block (16 KB)

#define WAITVM(N) asm volatile("s_waitcnt vmcnt(" #N ")" ::: "memory")
#define PIN4(v) asm volatile("" :: "v"((v).x), "v"((v).y), "v"((v).z), "v"((v).w))

__device__ __forceinline__ float elu_f(float x) {
    return x > 0.f ? x : (__expf(x) - 1.f);
}
__device__ __forceinline__ float rlf(float v, int l) {
    return __uint_as_float(__builtin_amdgcn_readlane(__float_as_uint(v), (unsigned)l));
}
__device__ __forceinline__ float f4c(const float4& v, int r) {
    return r == 0 ? v.x : r == 1 ? v.y : r == 2 ? v.z : v.w;
}

// Unit slot map: lane L, A-reg r (0..3) <-> h = L+64r  [exception (63,3) -> h=510]
//                lane L, B-reg 4+r     <-> h = 255+L+64r [exception (63,3) -> h=511]
__device__ __forceinline__ int pmap(int h) {
    if (h == 510) return 255;
    if (h == 511) return 511;
    return (h < 255) ? (4 * (h & 63) + (h >> 6))
                     : (256 + 4 * ((h - 255) & 63) + ((h - 255) >> 6));
}
__device__ __forceinline__ int p4map(int j) {      // j in [0,256): column map
    return 4 * (j & 63) + (j >> 6);
}
__device__ __forceinline__ int w1base(int hp) {    // m at +0, l at +512
    return (hp <= 254) ? hp * TS
         : (hp <= 509) ? (hp - 255) * TS + 1024
         : 255 * TS + ((hp == 510) ? 0 : 1024);
}
__device__ __forceinline__ int wobase(int hp) {    // m at +0, l at +256
    return (hp <= 254) ? hp * TS + 3072
         : (hp <= 509) ? (hp - 255) * TS + 3584
         : 255 * TS + ((hp == 510) ? 2048 : 2560);
}

// Tape block i (4096 floats), rows lane-packed [pos = p(h) or p4(j)]:
//  [0/512]    W1T[i]     m/l     [1024/1536] W1T[i+255] m/l
//  [2048/2560] W0T[i]    m/l     [3072/3328] WoT[i]     m/l (256)
//  [3584/3840] WoT[i+255] m/l
// Block 255 = appendix: W1T[510] m/l @0/512, W1T[511] m/l @1024/1536,
//  WoT[510] m/l @2048/2304, WoT[511] m/l @2560/2816.  [3072..4095 unused]
__global__ __launch_bounds__(256) void prep(
    const float* __restrict__ w0m_, const float* __restrict__ w0l_,
    const float* __restrict__ w1m_, const float* __restrict__ w1l_,
    const float* __restrict__ wom_, const float* __restrict__ wol_,
    float* __restrict__ tape)
{
    __shared__ float tm[32][33], tl[32][33];
    const int tx = threadIdx.x & 31, ty = threadIdx.x >> 5;
    const unsigned b = blockIdx.x;

    if (b < 256) {                              // W1: 16 h-tiles x 16 hp-tiles
        const int h0 = (int)(b >> 4) << 5, hp0 = (int)(b & 15) << 5;
        #pragma unroll
        for (int j = 0; j < 4; ++j) {
            int r = ty + 8 * j;
            tm[r][tx] = w1m_[(h0 + r) * HH + hp0 + tx];
            tl[r][tx] = w1l_[(h0 + r) * HH + hp0 + tx];
        }
        __syncthreads();
        #pragma unroll
        for (int j = 0; j < 4; ++j) {
            int hp = hp0 + ty + 8 * j;
            int h  = h0 + tx;
            int dh_h = (h <= 254) ? h + 1 : (h <= 509 ? h - 254 : h - 509);
            int dh_p = (hp <= 254) ? hp + 1 : (hp <= 509 ? hp - 254 : hp - 509);
            float mask = (dh_h >= dh_p) ? 1.f : 0.f;
            int base = w1base(hp), p = pmap(h);
            tape[base + p]       = mask * tm[tx][ty + 8 * j];
            tape[base + 512 + p] = mask * tl[tx][ty + 8 * j];
        }
    } else if (b < 384) {                       // W0: 16 h-tiles x 8 i-tiles
        const int b2 = (int)b - 256;
        const int h0 = (b2 >> 3) << 5, i0 = (b2 & 7) << 5;
        #pragma unroll
        for (int j = 0; j < 4; ++j) {
            int r = ty + 8 * j;
            tm[r][tx] = w0m_[(h0 + r) * DD + i0 + tx];
            tl[r][tx] = w0l_[(h0 + r) * DD + i0 + tx];
        }
        __syncthreads();
        #pragma unroll
        for (int j = 0; j < 4; ++j) {
            int i = i0 + ty + 8 * j;
            int h = h0 + tx;
            int p = pmap(h);
            tape[i * TS + 2048 + p] = tm[tx][ty + 8 * j];
            tape[i * TS + 2560 + p] = tl[tx][ty + 8 * j];
        }
    } else {                                    // Wo: 8 j-tiles x 16 hp-tiles
        const int b3 = (int)b - 384;
        const int j0 = (b3 >> 4) << 5, hp0 = (b3 & 15) << 5;
        #pragma unroll
        for (int j = 0; j < 4; ++j) {
            int r = ty + 8 * j;
            tm[r][tx] = wom_[(j0 + r) * HH + hp0 + tx];
            tl[r][tx] = wol_[(j0 + r) * HH + hp0 + tx];
        }
        __syncthreads();
        #pragma unroll
        for (int j = 0; j < 4; ++j) {
            int hp = hp0 + ty + 8 * j;
            int jj = j0 + tx;
            int base = wobase(hp), p = p4map(jj);
            tape[base + p]       = tm[tx][ty + 8 * j];
            tape[base + 256 + p] = tl[tx][ty + 8 * j];
        }
    }
}

// ================================ main =====================================
// stage one 16 KB group into an LDS ring slot via direct-to-LDS DMA.
__device__ __forceinline__ void stage16(const float* g, float* l, int lane) {
    #pragma unroll
    for (int k = 0; k < 16; ++k) {
        __builtin_amdgcn_global_load_lds(
            (const __attribute__((address_space(1))) void*)(g + 256 * k + 4 * lane),
            (__attribute__((address_space(3))) void*)(l + 256 * k),
            16, 0, 0);
    }
}

struct WSet { float4 w[16]; };

// LDS -> registers in use order: a0 weights first, then layer-1, then output.
__device__ __forceinline__ void rdW(WSet& S, const float* b, int lane) {
    const float4* p = (const float4*)b;
    S.w[8]  = p[64 * 8 + lane];  S.w[9]  = p[64 * 9 + lane];
    S.w[10] = p[64 * 10 + lane]; S.w[11] = p[64 * 11 + lane];
    S.w[0]  = p[64 * 0 + lane];  S.w[4]  = p[64 * 4 + lane];
    S.w[1]  = p[64 * 1 + lane];  S.w[5]  = p[64 * 5 + lane];
    S.w[2]  = p[64 * 2 + lane];  S.w[6]  = p[64 * 6 + lane];
    S.w[3]  = p[64 * 3 + lane];  S.w[7]  = p[64 * 7 + lane];
    S.w[12] = p[64 * 12 + lane]; S.w[14] = p[64 * 14 + lane];
    S.w[13] = p[64 * 13 + lane]; S.w[15] = p[64 * 15 + lane];
}
__device__ __forceinline__ void pinW(const WSet& S) {
    #pragma unroll
    for (int k = 0; k < 16; ++k) PIN4(S.w[k]);
}

// Fused step: both nets, one wave.  v passed in (broadcast by caller).
// w[0..3]=W1T[i] mA,mB,lA,lB  w[4..7]=W1T[i+255] mA,mB,lA,lB
// w[8..11]=W0T[i] mA,mB,lA,lB  w[12..15]=WoT[i]m, WoT[i]l, WoT[i+255]m, WoT[i+255]l
template<int Q, int EX>
__device__ __forceinline__ void stepF(
    int tl, int lane, float v, const WSet& S,
    float (&a0m)[8], float (&a0l)[8], float (&a1m)[8], float (&a1l)[8],
    float (&Rm)[4], float (&Rl)[4], float (&yv)[4],
    const float4& exmA, const float4& exmB, const float4& exlA, const float4& exlB,
    const float4& exwm, const float4& exwl)
{
    yv[Q] = (lane == tl) ? v : yv[Q];

    #pragma unroll
    for (int r = Q; r < 4; ++r) {
        a0m[r]     += v * f4c(S.w[8], r);
        a0m[4 + r] += v * f4c(S.w[9], r);
        a0l[r]     += v * f4c(S.w[10], r);
        a0l[4 + r] += v * f4c(S.w[11], r);
    }

    float p0m = elu_f(rlf(a0m[Q], tl)),     p0l = elu_f(rlf(a0l[Q], tl));
    float p1m = elu_f(rlf(a0m[4 + Q], tl)), p1l = elu_f(rlf(a0l[4 + Q], tl));
    float p2m = 0.f, p2l = 0.f;
    if (EX) {
        p2m = elu_f(rlf(a0m[EX == 1 ? 3 : 7], 63));
        p2l = elu_f(rlf(a0l[EX == 1 ? 3 : 7], 63));
    }

    #pragma unroll
    for (int r = Q; r < 4; ++r) {
        a1m[r]     += f4c(S.w[0], r) * p0m + f4c(S.w[4], r) * p1m;
        a1m[4 + r] += f4c(S.w[1], r) * p0m + f4c(S.w[5], r) * p1m;
        a1l[r]     += f4c(S.w[2], r) * p0l + f4c(S.w[6], r) * p1l;
        a1l[4 + r] += f4c(S.w[3], r) * p0l + f4c(S.w[7], r) * p1l;
    }
    if (EX) {
        #pragma unroll
        for (int r = 0; r < 4; ++r) {
            a1m[r]     += f4c(exmA, r) * p2m;
            a1m[4 + r] += f4c(exmB, r) * p2m;
            a1l[r]     += f4c(exlA, r) * p2l;
            a1l[4 + r] += f4c(exlB, r) * p2l;
        }
    }

    float q0m = elu_f(rlf(a1m[Q], tl)),     q0l = elu_f(rlf(a1l[Q], tl));
    float q1m = elu_f(rlf(a1m[4 + Q], tl)), q1l = elu_f(rlf(a1l[4 + Q], tl));
    float q2m = 0.f, q2l = 0.f;
    if (EX) {
        q2m = elu_f(rlf(a1m[EX == 1 ? 3 : 7], 63));
        q2l = elu_f(rlf(a1l[EX == 1 ? 3 : 7], 63));
    }

    #pragma unroll
    for (int r = Q; r < 4; ++r) {
        Rm[r] += f4c(S.w[12], r) * q0m + f4c(S.w[14], r) * q1m;
        Rl[r] += f4c(S.w[13], r) * q0l + f4c(S.w[15], r) * q1l;
    }
    if (EX) {
        #pragma unroll
        for (int r = 0; r < 4; ++r) {
            Rm[r] += f4c(exwm, r) * q2m;
            Rl[r] += f4c(exwl, r) * q2l;
        }
    }
}

// 2 waves: wave0 = fused consumer (both nets), wave1 = LDS producer.
// Producer invariant: at barrier t, slots <= t+1 are LDS-resident.
// The cross-step scalar chain never touches LDS: lane t+1 owns BOTH
// Rm and Rl columns for t+1, computes v locally; one readlane broadcasts.
__global__ __launch_bounds__(128, 1) void made_main(
    const float* __restrict__ x,
    const float* __restrict__ mu_b0, const float* __restrict__ mu_b1,
    const float* __restrict__ mu_bo,
    const float* __restrict__ lv_b0, const float* __restrict__ lv_b1,
    const float* __restrict__ lv_bo,
    const float* __restrict__ tape,
    float* __restrict__ out)
{
    __shared__ __align__(16) float buf[4][TS];
    const int row  = blockIdx.x;
    const int lane = threadIdx.x & 63;
    const int wid  = threadIdx.x >> 6;

    const float4 d4 = make_float4(0.f, 0.f, 0.f, 0.f);

    // ===== wave 1: LDS producer =====
    if (wid == 1) {
        #pragma unroll
        for (int g = 0; g < 3; ++g)
            stage16(tape + (size_t)g * TS, &buf[g][0], lane);
        #pragma unroll 1
        for (int t = 0; t < 255; ++t) {
            if (t < 253) { WAITVM(16); } else { WAITVM(0); }
            __builtin_amdgcn_s_barrier();        // release step t (slot t+1 ready)
            __builtin_amdgcn_sched_barrier(0);
            int g = t + 3;
            if (g < 255)
                stage16(tape + (size_t)g * TS, &buf[g & 3][0], lane);
        }
        return;
    }

    // ===== wave 0: fused consumer =====
    float a0m[8], a0l[8], a1m[8], a1l[8], Rm[4], Rl[4], yv[4];
    float xv[4], bmv[4], blv[4];
    #pragma unroll
    for (int r = 0; r < 4; ++r) {
        a0m[r]     = mu_b0[lane + 64 * r];
        a0m[4 + r] = mu_b0[255 + lane + 64 * r];
        a0l[r]     = lv_b0[lane + 64 * r];
        a0l[4 + r] = lv_b0[255 + lane + 64 * r];
        a1m[r]     = mu_b1[lane + 64 * r];
        a1m[4 + r] = mu_b1[255 + lane + 64 * r];
        a1l[r]     = lv_b1[lane + 64 * r];
        a1l[4 + r] = lv_b1[255 + lane + 64 * r];
        Rm[r] = 0.f; Rl[r] = 0.f; yv[r] = 0.f;
        xv[r]  = x[row * DD + 64 * r + lane];
        bmv[r] = mu_bo[64 * r + lane];
        blv[r] = lv_bo[64 * r + lane];
    }
    if (lane == 63) {   // (63,3) slots host h=510 (A) and h=511 (B)
        a0m[3] = mu_b0[510]; a0m[7] = mu_b0[511];
        a0l[3] = lv_b0[510]; a0l[7] = lv_b0[511];
        a1m[3] = mu_b1[510]; a1m[7] = mu_b1[511];
        a1l[3] = lv_b1[510]; a1l[7] = lv_b1[511];
    }

    // appendix preloads (dead after steps 0/1)
    const float4* a4 = (const float4*)(tape + 255 * TS);
    float4 e510mA = a4[lane],       e510mB = a4[64 + lane];
    float4 e510lA = a4[128 + lane], e510lB = a4[192 + lane];
    float4 e511mA = a4[256 + lane], e511mB = a4[320 + lane];
    float4 e511lA = a4[384 + lane], e511lB = a4[448 + lane];
    float4 wo510m = a4[512 + lane], wo510l = a4[576 + lane];
    float4 wo511m = a4[640 + lane], wo511l = a4[704 + lane];

    float ls_part = 0.f;
    float vloc;
    {   // t = 0 scalars (R = 0): lane 0 owns column 0 of both nets
        float d0  = xv[0] - (Rm[0] + bmv[0]);
        float ls0 = 0.5f * (Rl[0] + blv[0]);
        float s0  = __fdividef(1.f, __expf(ls0) + 1e-12f);
        ls_part += (lane == 0) ? ls0 : 0.f;
        vloc = d0 * s0;
    }

    WSet W;

    // ---- step 0 (EX h=510), slot 0 (read exposed once) ----
    __syncthreads();
    rdW(W, &buf[0][0], lane);
    {
        float v = rlf(vloc, 0);
        stepF<0, 1>(0, lane, v, W, a0m, a0l, a1m, a1l, Rm, Rl, yv,
                    e510mA, e510mB, e510lA, e510lB, wo510m, wo510l);
        rdW(W, &buf[1][0], lane);
        float d_  = xv[0] - (Rm[0] + bmv[0]);
        float ls_ = 0.5f * (Rl[0] + blv[0]);
        float s_  = __fdividef(1.f, __expf(ls_) + 1e-12f);
        ls_part += (lane == 1) ? ls_ : 0.f;
        vloc = d_ * s_;
        pinW(W);
    }

    // ---- step 1 (EX h=511), slot 1 ----
    __syncthreads();
    {
        float v = rlf(vloc, 1);
        stepF<0, 2>(1, lane, v, W, a0m, a0l, a1m, a1l, Rm, Rl, yv,
                    e511mA, e511mB, e511lA, e511lB, wo511m, wo511l);
        rdW(W, &buf[2][0], lane);
        float d_  = xv[0] - (Rm[0] + bmv[0]);
        float ls_ = 0.5f * (Rl[0] + blv[0]);
        float s_  = __fdividef(1.f, __expf(ls_) + 1e-12f);
        ls_part += (lane == 2) ? ls_ : 0.f;
        vloc = d_ * s_;
        pinW(W);
    }

#define FBODY(Q, tt, Qn, tn, PREF)                                            \
    {                                                                         \
        __syncthreads();                                                      \
        float v_ = rlf(vloc, (tt) & 63);                                      \
        stepF<Q, 0>((tt) & 63, lane, v_, W, a0m, a0l, a1m, a1l, Rm, Rl, yv,   \
                    d4, d4, d4, d4, d4, d4);                                  \
        if (PREF) rdW(W, &buf[((tt) + 1) & 3][0], lane);                      \
        float dn_  = xv[Qn] - (Rm[Qn] + bmv[Qn]);                             \
        float lsn_ = 0.5f * (Rl[Qn] + blv[Qn]);                               \
        float sn_  = __fdividef(1.f, __expf(lsn_) + 1e-12f);                  \
        ls_part += (lane == (tn)) ? lsn_ : 0.f;                               \
        vloc = dn_ * sn_;                                                     \
        if (PREF) pinW(W);                                                    \
    }

    #pragma unroll 1
    for (int t = 2; t < 63; ++t)    FBODY(0, t, 0, t + 1, 1)
    FBODY(0, 63, 1, 0, 1)
    #pragma unroll 1
    for (int t = 64; t < 127; ++t)  FBODY(1, t, 1, t - 63, 1)
    FBODY(1, 127, 2, 0, 1)
    #pragma unroll 1
    for (int t = 128; t < 191; ++t) FBODY(2, t, 2, t - 127, 1)
    FBODY(2, 191, 3, 0, 1)
    #pragma unroll 1
    for (int t = 192; t < 254; ++t) FBODY(3, t, 3, t - 191, 1)
    FBODY(3, 254, 3, 63, 0)
#undef FBODY

    // ---- step 255: output only (v_255 sits in lane 63's vloc) ----
    yv[3] = (lane == 63) ? vloc : yv[3];

    #pragma unroll
    for (int r = 0; r < 4; ++r) out[row * DD + 64 * r + lane] = yv[r];

    #pragma unroll
    for (int off = 32; off; off >>= 1)
        ls_part += __shfl_down(ls_part, off);
    if (lane == 0) out[BB * DD + row] = ls_part;
}

extern "C" void kernel_launch(void* const* d_in, const int* in_sizes, int n_in,
                              void* d_out, int out_size, void* d_ws, size_t ws_size,
                              hipStream_t stream) {
    const float* x     = (const float*)d_in[0];
    const float* mu_W0 = (const float*)d_in[1];
    const float* mu_b0 = (const float*)d_in[2];
    const float* mu_W1 = (const float*)d_in[3];
    const float* mu_b1 = (const float*)d_in[4];
    const float* mu_Wo = (const float*)d_in[5];
    const float* mu_bo = (const float*)d_in[6];
    const float* lv_W0 = (const float*)d_in[7];
    const float* lv_b0 = (const float*)d_in[8];
    const float* lv_W1 = (const float*)d_in[9];
    const float* lv_b1 = (const float*)d_in[10];
    const float* lv_Wo = (const float*)d_in[11];
    const float* lv_bo = (const float*)d_in[12];

    float* tape = (float*)d_ws;   // 4 MiB

    prep<<<512, 256, 0, stream>>>(mu_W0, lv_W0, mu_W1, lv_W1, mu_Wo, lv_Wo, tape);
    made_main<<<BB, 128, 0, stream>>>(x, mu_b0, mu_b1, mu_bo,
                                      lv_b0, lv_b1, lv_bo, tape, (float*)d_out);
}

// Round 9
// 174.639 us; speedup vs baseline: 1.0214x; 1.0214x over previous
//
#include <hip/hip_runtime.h>

#define DD 256
#define HH 512
#define BB 128
#define TS 4096   // floats per tape block (16 KB)

#define WAITVM(N) asm volatile("s_waitcnt vmcnt(" #N ")" ::: "memory")
#define WAITLGKM0() asm volatile("s_waitcnt lgkmcnt(0)" ::: "memory")
#define SBAR() do { __builtin_amdgcn_s_barrier(); __builtin_amdgcn_sched_barrier(0); } while (0)

__device__ __forceinline__ float elu_f(float x) {
    return x > 0.f ? x : (__expf(x) - 1.f);
}
__device__ __forceinline__ float rlf(float v, int l) {
    return __uint_as_float(__builtin_amdgcn_readlane(__float_as_uint(v), (unsigned)l));
}
__device__ __forceinline__ float f4c(const float4& v, int r) {
    return r == 0 ? v.x : r == 1 ? v.y : r == 2 ? v.z : v.w;
}

// Unit slot map: lane L, A-reg r (0..3) <-> h = L+64r  [exception (63,3) -> h=510]
//                lane L, B-reg 4+r     <-> h = 255+L+64r [exception (63,3) -> h=511]
__device__ __forceinline__ int pmap(int h) {
    if (h == 510) return 255;
    if (h == 511) return 511;
    return (h < 255) ? (4 * (h & 63) + (h >> 6))
                     : (256 + 4 * ((h - 255) & 63) + ((h - 255) >> 6));
}
__device__ __forceinline__ int p4map(int j) {      // j in [0,256): column map
    return 4 * (j & 63) + (j >> 6);
}
__device__ __forceinline__ int w1base(int hp) {    // m at +0, l at +512
    return (hp <= 254) ? hp * TS
         : (hp <= 509) ? (hp - 255) * TS + 1024
         : 255 * TS + ((hp == 510) ? 0 : 1024);
}
__device__ __forceinline__ int wobase(int hp) {    // m at +0, l at +256
    return (hp <= 254) ? hp * TS + 3072
         : (hp <= 509) ? (hp - 255) * TS + 3584
         : 255 * TS + ((hp == 510) ? 2048 : 2560);
}

// Tape block i (4096 floats), rows lane-packed [pos = p(h) or p4(j)]:
//  [0/512]    W1T[i]     m/l     [1024/1536] W1T[i+255] m/l
//  [2048/2560] W0T[i]    m/l     [3072/3328] WoT[i]     m/l (256)
//  [3584/3840] WoT[i+255] m/l
// Block 255 = appendix: W1T[510] m/l @0/512, W1T[511] m/l @1024/1536,
//  WoT[510] m/l @2048/2304, WoT[511] m/l @2560/2816.  [3072..4095 unused]
__global__ __launch_bounds__(256) void prep(
    const float* __restrict__ w0m_, const float* __restrict__ w0l_,
    const float* __restrict__ w1m_, const float* __restrict__ w1l_,
    const float* __restrict__ wom_, const float* __restrict__ wol_,
    float* __restrict__ tape)
{
    __shared__ float tm[32][33], tl[32][33];
    const int tx = threadIdx.x & 31, ty = threadIdx.x >> 5;
    const unsigned b = blockIdx.x;

    if (b < 256) {                              // W1: 16 h-tiles x 16 hp-tiles
        const int h0 = (int)(b >> 4) << 5, hp0 = (int)(b & 15) << 5;
        #pragma unroll
        for (int j = 0; j < 4; ++j) {
            int r = ty + 8 * j;
            tm[r][tx] = w1m_[(h0 + r) * HH + hp0 + tx];
            tl[r][tx] = w1l_[(h0 + r) * HH + hp0 + tx];
        }
        __syncthreads();
        #pragma unroll
        for (int j = 0; j < 4; ++j) {
            int hp = hp0 + ty + 8 * j;
            int h  = h0 + tx;
            int dh_h = (h <= 254) ? h + 1 : (h <= 509 ? h - 254 : h - 509);
            int dh_p = (hp <= 254) ? hp + 1 : (hp <= 509 ? hp - 254 : hp - 509);
            float mask = (dh_h >= dh_p) ? 1.f : 0.f;
            int base = w1base(hp), p = pmap(h);
            tape[base + p]       = mask * tm[tx][ty + 8 * j];
            tape[base + 512 + p] = mask * tl[tx][ty + 8 * j];
        }
    } else if (b < 384) {                       // W0: 16 h-tiles x 8 i-tiles
        const int b2 = (int)b - 256;
        const int h0 = (b2 >> 3) << 5, i0 = (b2 & 7) << 5;
        #pragma unroll
        for (int j = 0; j < 4; ++j) {
            int r = ty + 8 * j;
            tm[r][tx] = w0m_[(h0 + r) * DD + i0 + tx];
            tl[r][tx] = w0l_[(h0 + r) * DD + i0 + tx];
        }
        __syncthreads();
        #pragma unroll
        for (int j = 0; j < 4; ++j) {
            int i = i0 + ty + 8 * j;
            int h = h0 + tx;
            int p = pmap(h);
            tape[i * TS + 2048 + p] = tm[tx][ty + 8 * j];
            tape[i * TS + 2560 + p] = tl[tx][ty + 8 * j];
        }
    } else {                                    // Wo: 8 j-tiles x 16 hp-tiles
        const int b3 = (int)b - 384;
        const int j0 = (b3 >> 4) << 5, hp0 = (b3 & 15) << 5;
        #pragma unroll
        for (int j = 0; j < 4; ++j) {
            int r = ty + 8 * j;
            tm[r][tx] = wom_[(j0 + r) * HH + hp0 + tx];
            tl[r][tx] = wol_[(j0 + r) * HH + hp0 + tx];
        }
        __syncthreads();
        #pragma unroll
        for (int j = 0; j < 4; ++j) {
            int hp = hp0 + ty + 8 * j;
            int jj = j0 + tx;
            int base = wobase(hp), p = p4map(jj);
            tape[base + p]       = tm[tx][ty + 8 * j];
            tape[base + 256 + p] = tl[tx][ty + 8 * j];
        }
    }
}

// ================================ main =====================================
struct MSet { float4 w8, w9, w0, w4, w1, w5, w12, w14; };
struct LSet { float4 w10, w11, w2, w6, w3, w7, w13, w15; };

// direct global -> register half-set loads (tape is L2-resident: each XCD's
// 16 blocks share the same 4 MiB tape = exactly one L2).
__device__ __forceinline__ void ldM(MSet& S, const float* g, int lane) {
    const float4* p = (const float4*)g;
    S.w8  = p[64 * 8 + lane];  S.w9  = p[64 * 9 + lane];
    S.w0  = p[64 * 0 + lane];  S.w4  = p[64 * 4 + lane];
    S.w1  = p[64 * 1 + lane];  S.w5  = p[64 * 5 + lane];
    S.w12 = p[64 * 12 + lane]; S.w14 = p[64 * 14 + lane];
}
__device__ __forceinline__ void ldL(LSet& S, const float* g, int lane) {
    const float4* p = (const float4*)g;
    S.w10 = p[64 * 10 + lane]; S.w11 = p[64 * 11 + lane];
    S.w2  = p[64 * 2 + lane];  S.w6  = p[64 * 6 + lane];
    S.w3  = p[64 * 3 + lane];  S.w7  = p[64 * 7 + lane];
    S.w13 = p[64 * 13 + lane]; S.w15 = p[64 * 15 + lane];
}

// ---- mu-net half step ----
template<int Q, int EX>
__device__ __forceinline__ void stepM(
    int tl, int lane, float v, const MSet& S,
    float (&a0m)[8], float (&a1m)[8], float (&Rm)[4], float (&yv)[4],
    const float4& exA, const float4& exB, const float4& exW)
{
    yv[Q] = (lane == tl) ? v : yv[Q];

    #pragma unroll
    for (int r = Q; r < 4; ++r) {
        a0m[r]     += v * f4c(S.w8, r);
        a0m[4 + r] += v * f4c(S.w9, r);
    }
    float p0 = elu_f(rlf(a0m[Q], tl));
    float p1 = elu_f(rlf(a0m[4 + Q], tl));
    float p2 = 0.f;
    if (EX) p2 = elu_f(rlf(a0m[EX == 1 ? 3 : 7], 63));

    #pragma unroll
    for (int r = Q; r < 4; ++r) {
        a1m[r]     += f4c(S.w0, r) * p0 + f4c(S.w4, r) * p1;
        a1m[4 + r] += f4c(S.w1, r) * p0 + f4c(S.w5, r) * p1;
    }
    if (EX) {
        #pragma unroll
        for (int r = 0; r < 4; ++r) {
            a1m[r]     += f4c(exA, r) * p2;
            a1m[4 + r] += f4c(exB, r) * p2;
        }
    }

    float q0 = elu_f(rlf(a1m[Q], tl));
    float q1 = elu_f(rlf(a1m[4 + Q], tl));
    float q2 = 0.f;
    if (EX) q2 = elu_f(rlf(a1m[EX == 1 ? 3 : 7], 63));

    #pragma unroll
    for (int r = Q; r < 4; ++r)
        Rm[r] += f4c(S.w12, r) * q0 + f4c(S.w14, r) * q1;
    if (EX) {
        #pragma unroll
        for (int r = 0; r < 4; ++r) Rm[r] += f4c(exW, r) * q2;
    }
}

// ---- logvar-net half step ----
template<int Q, int EX>
__device__ __forceinline__ void stepL(
    int tl, int lane, float v, const LSet& S,
    float (&a0l)[8], float (&a1l)[8], float (&Rl)[4],
    const float4& exA, const float4& exB, const float4& exW)
{
    #pragma unroll
    for (int r = Q; r < 4; ++r) {
        a0l[r]     += v * f4c(S.w10, r);
        a0l[4 + r] += v * f4c(S.w11, r);
    }
    float p0 = elu_f(rlf(a0l[Q], tl));
    float p1 = elu_f(rlf(a0l[4 + Q], tl));
    float p2 = 0.f;
    if (EX) p2 = elu_f(rlf(a0l[EX == 1 ? 3 : 7], 63));

    #pragma unroll
    for (int r = Q; r < 4; ++r) {
        a1l[r]     += f4c(S.w2, r) * p0 + f4c(S.w6, r) * p1;
        a1l[4 + r] += f4c(S.w3, r) * p0 + f4c(S.w7, r) * p1;
    }
    if (EX) {
        #pragma unroll
        for (int r = 0; r < 4; ++r) {
            a1l[r]     += f4c(exA, r) * p2;
            a1l[4 + r] += f4c(exB, r) * p2;
        }
    }

    float q0 = elu_f(rlf(a1l[Q], tl));
    float q1 = elu_f(rlf(a1l[4 + Q], tl));
    float q2 = 0.f;
    if (EX) q2 = elu_f(rlf(a1l[EX == 1 ? 3 : 7], 63));

    #pragma unroll
    for (int r = Q; r < 4; ++r)
        Rl[r] += f4c(S.w13, r) * q0 + f4c(S.w15, r) * q1;
    if (EX) {
        #pragma unroll
        for (int r = 0; r < 4; ++r) Rl[r] += f4c(exW, r) * q2;
    }
}

// 2 waves, no producer, no weight LDS.  Each wave owns a 2-bank direct
// global->register pipeline over the tape (bank t&1 consumed at step t,
// reloaded for t+2 right after last use; counted WAITVM(8) per step).
// Barrier = raw s_barrier with only lgkmcnt(0) drained (the 16 B exch
// write) -- in-flight weight loads are never drained at the barrier.
__global__ __launch_bounds__(128, 1) void made_main(
    const float* __restrict__ x,
    const float* __restrict__ mu_b0, const float* __restrict__ mu_b1,
    const float* __restrict__ mu_bo,
    const float* __restrict__ lv_b0, const float* __restrict__ lv_b1,
    const float* __restrict__ lv_bo,
    const float* __restrict__ tape,
    float* __restrict__ out)
{
    __shared__ __align__(8) float exch[2][2];  // [parity][0]=d (M), [1]=s (L)
    const int row  = blockIdx.x;
    const int lane = threadIdx.x & 63;
    const int wid  = threadIdx.x >> 6;

    const float4 d4 = make_float4(0.f, 0.f, 0.f, 0.f);
    const float4* a4 = (const float4*)(tape + 255 * TS);

    if (wid == 0) {
        // =============================== M wave ============================
        float a0m[8], a1m[8], Rm[4], yv[4], xv[4], bmv[4];
        #pragma unroll
        for (int r = 0; r < 4; ++r) {
            a0m[r]     = mu_b0[lane + 64 * r];
            a0m[4 + r] = mu_b0[255 + lane + 64 * r];
            a1m[r]     = mu_b1[lane + 64 * r];
            a1m[4 + r] = mu_b1[255 + lane + 64 * r];
            Rm[r] = 0.f; yv[r] = 0.f;
            xv[r]  = x[row * DD + 64 * r + lane];
            bmv[r] = mu_bo[64 * r + lane];
        }
        if (lane == 63) {
            a0m[3] = mu_b0[510]; a0m[7] = mu_b0[511];
            a1m[3] = mu_b1[510]; a1m[7] = mu_b1[511];
        }
        float4 e510A = a4[lane],       e510B = a4[64 + lane];
        float4 e511A = a4[256 + lane], e511B = a4[320 + lane];
        float4 wo510 = a4[512 + lane], wo511 = a4[640 + lane];

        MSet WA, WB;
        ldM(WA, tape + 0 * TS, lane);
        ldM(WB, tape + 1 * TS, lane);

        {   // t = 0 scalar (R = 0), lane 0 owns column 0
            float d0 = xv[0] - (Rm[0] + bmv[0]);
            if (lane == 0) exch[0][0] = d0;
        }
        WAITVM(8);          // WA resident (WB in flight)
        WAITLGKM0();
        SBAR();

        // ---- step 0 (EX h=510), WA = group 0; reload WA <- group 2 ----
        {
            float2 ds_ = *(const float2*)&exch[0][0];
            float v_ = ds_.x * ds_.y;
            stepM<0, 1>(0, lane, v_, WA, a0m, a1m, Rm, yv, e510A, e510B, wo510);
            ldM(WA, tape + 2 * TS, lane);
            float dn_ = xv[0] - (Rm[0] + bmv[0]);
            if (lane == 1) exch[1][0] = dn_;
            WAITVM(8);
            WAITLGKM0();
            SBAR();
        }
        // ---- step 1 (EX h=511), WB = group 1; reload WB <- group 3 ----
        {
            float2 ds_ = *(const float2*)&exch[1][0];
            float v_ = ds_.x * ds_.y;
            stepM<0, 2>(1, lane, v_, WB, a0m, a1m, Rm, yv, e511A, e511B, wo511);
            ldM(WB, tape + 3 * TS, lane);
            float dn_ = xv[0] - (Rm[0] + bmv[0]);
            if (lane == 2) exch[0][0] = dn_;
            WAITVM(8);
            WAITLGKM0();
            SBAR();
        }

#define MBODY(Q, tt, Qn, tn, SC)                                              \
    {                                                                         \
        float2 ds_ = *(const float2*)&exch[(tt) & 1][0];                      \
        float v_ = ds_.x * ds_.y;                                             \
        stepM<Q, 0>((tt) - 64 * (Q), lane, v_, SC, a0m, a1m, Rm, yv,          \
                    d4, d4, d4);                                              \
        if ((tt) + 2 < 255) ldM(SC, tape + (size_t)((tt) + 2) * TS, lane);    \
        float dn_ = xv[Qn] - (Rm[Qn] + bmv[Qn]);                              \
        if (lane == (tn)) exch[((tt) + 1) & 1][0] = dn_;                      \
        if ((tt) < 253) { WAITVM(8); } else { WAITVM(0); }                    \
        WAITLGKM0();                                                          \
        SBAR();                                                               \
    }
        #pragma unroll 1
        for (int t = 2; t < 62; t += 2) {
            MBODY(0, t, 0, t + 1, WA)
            MBODY(0, t + 1, 0, t + 2, WB)
        }
        MBODY(0, 62, 0, 63, WA)
        MBODY(0, 63, 1, 0, WB)
        #pragma unroll 1
        for (int t = 64; t < 126; t += 2) {
            MBODY(1, t, 1, t - 63, WA)
            MBODY(1, t + 1, 1, t - 62, WB)
        }
        MBODY(1, 126, 1, 63, WA)
        MBODY(1, 127, 2, 0, WB)
        #pragma unroll 1
        for (int t = 128; t < 190; t += 2) {
            MBODY(2, t, 2, t - 127, WA)
            MBODY(2, t + 1, 2, t - 126, WB)
        }
        MBODY(2, 190, 2, 63, WA)
        MBODY(2, 191, 3, 0, WB)
        #pragma unroll 1
        for (int t = 192; t < 252; t += 2) {
            MBODY(3, t, 3, t - 191, WA)
            MBODY(3, t + 1, 3, t - 190, WB)
        }
        MBODY(3, 252, 3, 61, WA)
        MBODY(3, 253, 3, 62, WB)
        MBODY(3, 254, 3, 63, WA)
#undef MBODY

        // ---- step 255: output only (v_255 = d_255 * s_255 from exch[1]) ----
        {
            float2 dsF = *(const float2*)&exch[1][0];
            yv[3] = (lane == 63) ? dsF.x * dsF.y : yv[3];
        }
        #pragma unroll
        for (int r = 0; r < 4; ++r) out[row * DD + 64 * r + lane] = yv[r];
    } else {
        // =============================== L wave ============================
        float a0l[8], a1l[8], Rl[4], xv[4], blv[4];
        #pragma unroll
        for (int r = 0; r < 4; ++r) {
            a0l[r]     = lv_b0[lane + 64 * r];
            a0l[4 + r] = lv_b0[255 + lane + 64 * r];
            a1l[r]     = lv_b1[lane + 64 * r];
            a1l[4 + r] = lv_b1[255 + lane + 64 * r];
            Rl[r] = 0.f;
            xv[r]  = x[row * DD + 64 * r + lane];
            blv[r] = lv_bo[64 * r + lane];
        }
        if (lane == 63) {
            a0l[3] = lv_b0[510]; a0l[7] = lv_b0[511];
            a1l[3] = lv_b1[510]; a1l[7] = lv_b1[511];
        }
        float4 e510A = a4[128 + lane], e510B = a4[192 + lane];
        float4 e511A = a4[384 + lane], e511B = a4[448 + lane];
        float4 wo510 = a4[576 + lane], wo511 = a4[704 + lane];

        LSet WA, WB;
        ldL(WA, tape + 0 * TS, lane);
        ldL(WB, tape + 1 * TS, lane);

        float ls_part = 0.f;
        {   // t = 0 scalar (R = 0), lane 0 owns column 0
            float ls0 = 0.5f * (Rl[0] + blv[0]);
            float s0  = __fdividef(1.f, __expf(ls0) + 1e-12f);
            ls_part += (lane == 0) ? ls0 : 0.f;
            if (lane == 0) exch[0][1] = s0;
        }
        WAITVM(8);
        WAITLGKM0();
        SBAR();

        // ---- step 0 (EX h=510) ----
        {
            float2 ds_ = *(const float2*)&exch[0][0];
            float v_ = ds_.x * ds_.y;
            stepL<0, 1>(0, lane, v_, WA, a0l, a1l, Rl, e510A, e510B, wo510);
            ldL(WA, tape + 2 * TS, lane);
            float lsn_ = 0.5f * (Rl[0] + blv[0]);
            float sn_  = __fdividef(1.f, __expf(lsn_) + 1e-12f);
            ls_part += (lane == 1) ? lsn_ : 0.f;
            if (lane == 1) exch[1][1] = sn_;
            WAITVM(8);
            WAITLGKM0();
            SBAR();
        }
        // ---- step 1 (EX h=511) ----
        {
            float2 ds_ = *(const float2*)&exch[1][0];
            float v_ = ds_.x * ds_.y;
            stepL<0, 2>(1, lane, v_, WB, a0l, a1l, Rl, e511A, e511B, wo511);
            ldL(WB, tape + 3 * TS, lane);
            float lsn_ = 0.5f * (Rl[0] + blv[0]);
            float sn_  = __fdividef(1.f, __expf(lsn_) + 1e-12f);
            ls_part += (lane == 2) ? lsn_ : 0.f;
            if (lane == 2) exch[0][1] = sn_;
            WAITVM(8);
            WAITLGKM0();
            SBAR();
        }

#define LBODY(Q, tt, Qn, tn, SC)                                              \
    {                                                                         \
        float2 ds_ = *(const float2*)&exch[(tt) & 1][0];                      \
        float v_ = ds_.x * ds_.y;                                             \
        stepL<Q, 0>((tt) - 64 * (Q), lane, v_, SC, a0l, a1l, Rl, d4, d4, d4); \
        if ((tt) + 2 < 255) ldL(SC, tape + (size_t)((tt) + 2) * TS, lane);    \
        float lsn_ = 0.5f * (Rl[Qn] + blv[Qn]);                               \
        float sn_  = __fdividef(1.f, __expf(lsn_) + 1e-12f);                  \
        ls_part += (lane == (tn)) ? lsn_ : 0.f;                               \
        if (lane == (tn)) exch[((tt) + 1) & 1][1] = sn_;                      \
        if ((tt) < 253) { WAITVM(8); } else { WAITVM(0); }                    \
        WAITLGKM0();                                                          \
        SBAR();                                                               \
    }
        #pragma unroll 1
        for (int t = 2; t < 62; t += 2) {
            LBODY(0, t, 0, t + 1, WA)
            LBODY(0, t + 1, 0, t + 2, WB)
        }
        LBODY(0, 62, 0, 63, WA)
        LBODY(0, 63, 1, 0, WB)
        #pragma unroll 1
        for (int t = 64; t < 126; t += 2) {
            LBODY(1, t, 1, t - 63, WA)
            LBODY(1, t + 1, 1, t - 62, WB)
        }
        LBODY(1, 126, 1, 63, WA)
        LBODY(1, 127, 2, 0, WB)
        #pragma unroll 1
        for (int t = 128; t < 190; t += 2) {
            LBODY(2, t, 2, t - 127, WA)
            LBODY(2, t + 1, 2, t - 126, WB)
        }
        LBODY(2, 190, 2, 63, WA)
        LBODY(2, 191, 3, 0, WB)
        #pragma unroll 1
        for (int t = 192; t < 252; t += 2) {
            LBODY(3, t, 3, t - 191, WA)
            LBODY(3, t + 1, 3, t - 190, WB)
        }
        LBODY(3, 252, 3, 61, WA)
        LBODY(3, 253, 3, 62, WB)
        LBODY(3, 254, 3, 63, WA)
#undef LBODY

        // ---- t = 255: reduce ls and store ----
        #pragma unroll
        for (int off = 32; off; off >>= 1)
            ls_part += __shfl_down(ls_part, off);
        if (lane == 0) out[BB * DD + row] = ls_part;
    }
}

extern "C" void kernel_launch(void* const* d_in, const int* in_sizes, int n_in,
                              void* d_out, int out_size, void* d_ws, size_t ws_size,
                              hipStream_t stream) {
    const float* x     = (const float*)d_in[0];
    const float* mu_W0 = (const float*)d_in[1];
    const float* mu_b0 = (const float*)d_in[2];
    const float* mu_W1 = (const float*)d_in[3];
    const float* mu_b1 = (const float*)d_in[4];
    const float* mu_Wo = (const float*)d_in[5];
    const float* mu_bo = (const float*)d_in[6];
    const float* lv_W0 = (const float*)d_in[7];
    const float* lv_b0 = (const float*)d_in[8];
    const float* lv_W1 = (const float*)d_in[9];
    const float* lv_b1 = (const float*)d_in[10];
    const float* lv_Wo = (const float*)d_in[11];
    const float* lv_bo = (const float*)d_in[12];

    float* tape = (float*)d_ws;   // 4 MiB

    prep<<<512, 256, 0, stream>>>(mu_W0, lv_W0, mu_W1, lv_W1, mu_Wo, lv_Wo, tape);
    made_main<<<BB, 128, 0, stream>>>(x, mu_b0, mu_b1, mu_bo,
                                      lv_b0, lv_b1, lv_bo, tape, (float*)d_out);
}

// Round 10
// 153.726 us; speedup vs baseline: 1.1603x; 1.1360x over previous
//
#include <hip/hip_runtime.h>

#define DD 256
#define HH 512
#define BB 128
#define TS 4096   // floats per tape block (16 KB)

#define WAITVM(N) asm volatile("s_waitcnt vmcnt(" #N ")" ::: "memory")
#define PIN4(v) asm volatile("" :: "v"((v).x), "v"((v).y), "v"((v).z), "v"((v).w))

__device__ __forceinline__ float elu_f(float x) {
    return x > 0.f ? x : (__expf(x) - 1.f);
}
__device__ __forceinline__ float rlf(float v, int l) {
    return __uint_as_float(__builtin_amdgcn_readlane(__float_as_uint(v), (unsigned)l));
}
__device__ __forceinline__ float f4c(const float4& v, int r) {
    return r == 0 ? v.x : r == 1 ? v.y : r == 2 ? v.z : v.w;
}

// Unit slot map: lane L, A-reg r (0..3) <-> h = L+64r  [exception (63,3) -> h=510]
//                lane L, B-reg 4+r     <-> h = 255+L+64r [exception (63,3) -> h=511]
__device__ __forceinline__ int pmap(int h) {
    if (h == 510) return 255;
    if (h == 511) return 511;
    return (h < 255) ? (4 * (h & 63) + (h >> 6))
                     : (256 + 4 * ((h - 255) & 63) + ((h - 255) >> 6));
}
__device__ __forceinline__ int p4map(int j) {      // j in [0,256): column map
    return 4 * (j & 63) + (j >> 6);
}
__device__ __forceinline__ int w1base(int hp) {    // m at +0, l at +512
    return (hp <= 254) ? hp * TS
         : (hp <= 509) ? (hp - 255) * TS + 1024
         : 255 * TS + ((hp == 510) ? 0 : 1024);
}
__device__ __forceinline__ int wobase(int hp) {    // m at +0, l at +256
    return (hp <= 254) ? hp * TS + 3072
         : (hp <= 509) ? (hp - 255) * TS + 3584
         : 255 * TS + ((hp == 510) ? 2048 : 2560);
}

// Tape block i (4096 floats), rows lane-packed [pos = p(h) or p4(j)]:
//  [0/512]    W1T[i]     m/l     [1024/1536] W1T[i+255] m/l
//  [2048/2560] W0T[i]    m/l     [3072/3328] WoT[i]     m/l (256)
//  [3584/3840] WoT[i+255] m/l
// Block 255 = appendix: W1T[510] m/l @0/512, W1T[511] m/l @1024/1536,
//  WoT[510] m/l @2048/2304, WoT[511] m/l @2560/2816.  [3072..4095 unused]
__global__ __launch_bounds__(256) void prep(
    const float* __restrict__ w0m_, const float* __restrict__ w0l_,
    const float* __restrict__ w1m_, const float* __restrict__ w1l_,
    const float* __restrict__ wom_, const float* __restrict__ wol_,
    float* __restrict__ tape)
{
    __shared__ float tm[32][33], tl[32][33];
    const int tx = threadIdx.x & 31, ty = threadIdx.x >> 5;
    const unsigned b = blockIdx.x;

    if (b < 256) {                              // W1: 16 h-tiles x 16 hp-tiles
        const int h0 = (int)(b >> 4) << 5, hp0 = (int)(b & 15) << 5;
        #pragma unroll
        for (int j = 0; j < 4; ++j) {
            int r = ty + 8 * j;
            tm[r][tx] = w1m_[(h0 + r) * HH + hp0 + tx];
            tl[r][tx] = w1l_[(h0 + r) * HH + hp0 + tx];
        }
        __syncthreads();
        #pragma unroll
        for (int j = 0; j < 4; ++j) {
            int hp = hp0 + ty + 8 * j;
            int h  = h0 + tx;
            int dh_h = (h <= 254) ? h + 1 : (h <= 509 ? h - 254 : h - 509);
            int dh_p = (hp <= 254) ? hp + 1 : (hp <= 509 ? hp - 254 : hp - 509);
            float mask = (dh_h >= dh_p) ? 1.f : 0.f;
            int base = w1base(hp), p = pmap(h);
            tape[base + p]       = mask * tm[tx][ty + 8 * j];
            tape[base + 512 + p] = mask * tl[tx][ty + 8 * j];
        }
    } else if (b < 384) {                       // W0: 16 h-tiles x 8 i-tiles
        const int b2 = (int)b - 256;
        const int h0 = (b2 >> 3) << 5, i0 = (b2 & 7) << 5;
        #pragma unroll
        for (int j = 0; j < 4; ++j) {
            int r = ty + 8 * j;
            tm[r][tx] = w0m_[(h0 + r) * DD + i0 + tx];
            tl[r][tx] = w0l_[(h0 + r) * DD + i0 + tx];
        }
        __syncthreads();
        #pragma unroll
        for (int j = 0; j < 4; ++j) {
            int i = i0 + ty + 8 * j;
            int h = h0 + tx;
            int p = pmap(h);
            tape[i * TS + 2048 + p] = tm[tx][ty + 8 * j];
            tape[i * TS + 2560 + p] = tl[tx][ty + 8 * j];
        }
    } else {                                    // Wo: 8 j-tiles x 16 hp-tiles
        const int b3 = (int)b - 384;
        const int j0 = (b3 >> 4) << 5, hp0 = (b3 & 15) << 5;
        #pragma unroll
        for (int j = 0; j < 4; ++j) {
            int r = ty + 8 * j;
            tm[r][tx] = wom_[(j0 + r) * HH + hp0 + tx];
            tl[r][tx] = wol_[(j0 + r) * HH + hp0 + tx];
        }
        __syncthreads();
        #pragma unroll
        for (int j = 0; j < 4; ++j) {
            int hp = hp0 + ty + 8 * j;
            int jj = j0 + tx;
            int base = wobase(hp), p = p4map(jj);
            tape[base + p]       = tm[tx][ty + 8 * j];
            tape[base + 256 + p] = tl[tx][ty + 8 * j];
        }
    }
}

// ================================ main =====================================
// stage one 16 KB group into an LDS ring slot via direct-to-LDS DMA.
__device__ __forceinline__ void stage16(const float* g, float* l, int lane) {
    #pragma unroll
    for (int k = 0; k < 16; ++k) {
        __builtin_amdgcn_global_load_lds(
            (const __attribute__((address_space(1))) void*)(g + 256 * k + 4 * lane),
            (__attribute__((address_space(3))) void*)(l + 256 * k),
            16, 0, 0);
    }
}

struct MSet { float4 w8, w9, w0, w4, w1, w5, w12, w14; };
struct LSet { float4 w10, w11, w2, w6, w3, w7, w13, w15; };

__device__ __forceinline__ void rdM(MSet& S, const float* b, int lane) {
    const float4* p = (const float4*)b;
    S.w8  = p[64 * 8 + lane];  S.w9  = p[64 * 9 + lane];
    S.w0  = p[64 * 0 + lane];  S.w4  = p[64 * 4 + lane];
    S.w1  = p[64 * 1 + lane];  S.w5  = p[64 * 5 + lane];
    S.w12 = p[64 * 12 + lane]; S.w14 = p[64 * 14 + lane];
}
__device__ __forceinline__ void rdL(LSet& S, const float* b, int lane) {
    const float4* p = (const float4*)b;
    S.w10 = p[64 * 10 + lane]; S.w11 = p[64 * 11 + lane];
    S.w2  = p[64 * 2 + lane];  S.w6  = p[64 * 6 + lane];
    S.w3  = p[64 * 3 + lane];  S.w7  = p[64 * 7 + lane];
    S.w13 = p[64 * 13 + lane]; S.w15 = p[64 * 15 + lane];
}
__device__ __forceinline__ void pinM(const MSet& S) {
    PIN4(S.w8); PIN4(S.w9); PIN4(S.w0); PIN4(S.w4);
    PIN4(S.w1); PIN4(S.w5); PIN4(S.w12); PIN4(S.w14);
}
__device__ __forceinline__ void pinL(const LSet& S) {
    PIN4(S.w10); PIN4(S.w11); PIN4(S.w2); PIN4(S.w6);
    PIN4(S.w3); PIN4(S.w7); PIN4(S.w13); PIN4(S.w15);
}

// ---- mu-net half step ----
template<int Q, int EX>
__device__ __forceinline__ void stepM(
    int tl, int lane, float v, const MSet& S,
    float (&a0m)[8], float (&a1m)[8], float (&Rm)[4], float (&yv)[4],
    const float4& exA, const float4& exB, const float4& exW)
{
    yv[Q] = (lane == tl) ? v : yv[Q];

    #pragma unroll
    for (int r = Q; r < 4; ++r) {
        a0m[r]     += v * f4c(S.w8, r);
        a0m[4 + r] += v * f4c(S.w9, r);
    }
    float p0 = elu_f(rlf(a0m[Q], tl));
    float p1 = elu_f(rlf(a0m[4 + Q], tl));
    float p2 = 0.f;
    if (EX) p2 = elu_f(rlf(a0m[EX == 1 ? 3 : 7], 63));

    #pragma unroll
    for (int r = Q; r < 4; ++r) {
        a1m[r]     += f4c(S.w0, r) * p0 + f4c(S.w4, r) * p1;
        a1m[4 + r] += f4c(S.w1, r) * p0 + f4c(S.w5, r) * p1;
    }
    if (EX) {
        #pragma unroll
        for (int r = 0; r < 4; ++r) {
            a1m[r]     += f4c(exA, r) * p2;
            a1m[4 + r] += f4c(exB, r) * p2;
        }
    }

    float q0 = elu_f(rlf(a1m[Q], tl));
    float q1 = elu_f(rlf(a1m[4 + Q], tl));
    float q2 = 0.f;
    if (EX) q2 = elu_f(rlf(a1m[EX == 1 ? 3 : 7], 63));

    #pragma unroll
    for (int r = Q; r < 4; ++r)
        Rm[r] += f4c(S.w12, r) * q0 + f4c(S.w14, r) * q1;
    if (EX) {
        #pragma unroll
        for (int r = 0; r < 4; ++r) Rm[r] += f4c(exW, r) * q2;
    }
}

// ---- logvar-net half step ----
template<int Q, int EX>
__device__ __forceinline__ void stepL(
    int tl, int lane, float v, const LSet& S,
    float (&a0l)[8], float (&a1l)[8], float (&Rl)[4],
    const float4& exA, const float4& exB, const float4& exW)
{
    #pragma unroll
    for (int r = Q; r < 4; ++r) {
        a0l[r]     += v * f4c(S.w10, r);
        a0l[4 + r] += v * f4c(S.w11, r);
    }
    float p0 = elu_f(rlf(a0l[Q], tl));
    float p1 = elu_f(rlf(a0l[4 + Q], tl));
    float p2 = 0.f;
    if (EX) p2 = elu_f(rlf(a0l[EX == 1 ? 3 : 7], 63));

    #pragma unroll
    for (int r = Q; r < 4; ++r) {
        a1l[r]     += f4c(S.w2, r) * p0 + f4c(S.w6, r) * p1;
        a1l[4 + r] += f4c(S.w3, r) * p0 + f4c(S.w7, r) * p1;
    }
    if (EX) {
        #pragma unroll
        for (int r = 0; r < 4; ++r) {
            a1l[r]     += f4c(exA, r) * p2;
            a1l[4 + r] += f4c(exB, r) * p2;
        }
    }

    float q0 = elu_f(rlf(a1l[Q], tl));
    float q1 = elu_f(rlf(a1l[4 + Q], tl));
    float q2 = 0.f;
    if (EX) q2 = elu_f(rlf(a1l[EX == 1 ? 3 : 7], 63));

    #pragma unroll
    for (int r = Q; r < 4; ++r)
        Rl[r] += f4c(S.w13, r) * q0 + f4c(S.w15, r) * q1;
    if (EX) {
        #pragma unroll
        for (int r = 0; r < 4; ++r) Rl[r] += f4c(exW, r) * q2;
    }
}

// 3 waves: wave0 = mu-net (M), wave1 = logvar-net (L), wave2 = LDS producer.
// Producer invariant: at barrier t, slots <= t+1 are LDS-resident.
// Step body order (the round-10 change): read exch FIRST after the barrier
// (v's wait is then a counted lgkmcnt on one b64, not behind 8 b128 weight
// prefetches -- LDS returns in issue order), then issue the next-step
// weight prefetch, then compute.
__global__ __launch_bounds__(192, 1) void made_main(
    const float* __restrict__ x,
    const float* __restrict__ mu_b0, const float* __restrict__ mu_b1,
    const float* __restrict__ mu_bo,
    const float* __restrict__ lv_b0, const float* __restrict__ lv_b1,
    const float* __restrict__ lv_bo,
    const float* __restrict__ tape,
    float* __restrict__ out)
{
    __shared__ __align__(16) float buf[4][TS];
    __shared__ __align__(8) float exch[2][2];  // [parity][0]=d, [1]=s
    const int row  = blockIdx.x;
    const int lane = threadIdx.x & 63;
    const int wid  = threadIdx.x >> 6;

    const float4 d4 = make_float4(0.f, 0.f, 0.f, 0.f);

    // ===== wave 2: LDS producer =====
    if (wid == 2) {
        #pragma unroll
        for (int g = 0; g < 3; ++g)
            stage16(tape + (size_t)g * TS, &buf[g][0], lane);
        #pragma unroll 1
        for (int t = 0; t < 255; ++t) {
            if (t < 253) { WAITVM(16); } else { WAITVM(0); }
            __builtin_amdgcn_s_barrier();        // release step t (slot t+1 ready)
            __builtin_amdgcn_sched_barrier(0);
            int g = t + 3;
            if (g < 255)
                stage16(tape + (size_t)g * TS, &buf[g & 3][0], lane);
        }
        __builtin_amdgcn_s_barrier();            // final t=255 exchange
        return;
    }

    const float4* a4 = (const float4*)(tape + 255 * TS);

    if (wid == 0) {
        // =============================== M wave ============================
        float a0m[8], a1m[8], Rm[4], yv[4], xv[4], bmv[4];
        #pragma unroll
        for (int r = 0; r < 4; ++r) {
            a0m[r]     = mu_b0[lane + 64 * r];
            a0m[4 + r] = mu_b0[255 + lane + 64 * r];
            a1m[r]     = mu_b1[lane + 64 * r];
            a1m[4 + r] = mu_b1[255 + lane + 64 * r];
            Rm[r] = 0.f; yv[r] = 0.f;
            xv[r]  = x[row * DD + 64 * r + lane];
            bmv[r] = mu_bo[64 * r + lane];
        }
        if (lane == 63) {
            a0m[3] = mu_b0[510]; a0m[7] = mu_b0[511];
            a1m[3] = mu_b1[510]; a1m[7] = mu_b1[511];
        }
        float4 e510A = a4[lane],       e510B = a4[64 + lane];
        float4 e511A = a4[256 + lane], e511B = a4[320 + lane];
        float4 wo510 = a4[512 + lane], wo511 = a4[640 + lane];

        MSet A, B;

        {   // t = 0 scalar (R = 0): d0 owned by lane 0
            float d0 = xv[0] - (Rm[0] + bmv[0]);
            if (lane == 0) exch[0][0] = d0;
        }

        // ---- step 0 (EX h=510), slot 0; load A(slot0)+B(slot1) ----
        __syncthreads();
        {
            float2 ds0 = *(const float2*)&exch[0][0];
            float v0 = ds0.x * ds0.y;
            rdM(A, &buf[0][0], lane);
            rdM(B, &buf[1][0], lane);
            stepM<0, 1>(0, lane, v0, A, a0m, a1m, Rm, yv, e510A, e510B, wo510);
            float dn = xv[0] - (Rm[0] + bmv[0]);
            if (lane == 1) exch[1][0] = dn;
            pinM(B);
        }
        // ---- step 1 (EX h=511), B; prefetch A <- slot 2 ----
        __syncthreads();
        {
            float2 ds1 = *(const float2*)&exch[1][0];
            float v1 = ds1.x * ds1.y;
            rdM(A, &buf[2][0], lane);
            stepM<0, 2>(1, lane, v1, B, a0m, a1m, Rm, yv, e511A, e511B, wo511);
            float dn = xv[0] - (Rm[0] + bmv[0]);
            if (lane == 2) exch[0][0] = dn;
            pinM(A);
        }

#define MBODY(Q, tt, Qn, tn, SC, SN, PREF)                                    \
    {                                                                         \
        __syncthreads();                                                      \
        float2 ds_ = *(const float2*)&exch[(tt) & 1][0];                      \
        float v_ = ds_.x * ds_.y;                                             \
        if (PREF) rdM(SN, &buf[((tt) + 1) & 3][0], lane);                     \
        stepM<Q, 0>((tt) - 64 * (Q), lane, v_, SC, a0m, a1m, Rm, yv,          \
                    d4, d4, d4);                                              \
        float dn_ = xv[Qn] - (Rm[Qn] + bmv[Qn]);                              \
        if (lane == (tn)) exch[((tt) + 1) & 1][0] = dn_;                      \
        if (PREF) pinM(SN);                                                   \
    }
        #pragma unroll 1
        for (int t = 2; t < 62; t += 2) {
            MBODY(0, t, 0, t + 1, A, B, 1)
            MBODY(0, t + 1, 0, t + 2, B, A, 1)
        }
        MBODY(0, 62, 0, 63, A, B, 1)
        MBODY(0, 63, 1, 0, B, A, 1)
        #pragma unroll 1
        for (int t = 64; t < 126; t += 2) {
            MBODY(1, t, 1, t - 63, A, B, 1)
            MBODY(1, t + 1, 1, t - 62, B, A, 1)
        }
        MBODY(1, 126, 1, 63, A, B, 1)
        MBODY(1, 127, 2, 0, B, A, 1)
        #pragma unroll 1
        for (int t = 128; t < 190; t += 2) {
            MBODY(2, t, 2, t - 127, A, B, 1)
            MBODY(2, t + 1, 2, t - 126, B, A, 1)
        }
        MBODY(2, 190, 2, 63, A, B, 1)
        MBODY(2, 191, 3, 0, B, A, 1)
        #pragma unroll 1
        for (int t = 192; t < 252; t += 2) {
            MBODY(3, t, 3, t - 191, A, B, 1)
            MBODY(3, t + 1, 3, t - 190, B, A, 1)
        }
        MBODY(3, 252, 3, 61, A, B, 1)
        MBODY(3, 253, 3, 62, B, A, 1)
        MBODY(3, 254, 3, 63, A, B, 0)
#undef MBODY

        // ---- t = 255: output only ----
        __syncthreads();
        {
            float2 dsF = *(const float2*)&exch[1][0];
            yv[3] = (lane == 63) ? dsF.x * dsF.y : yv[3];
        }
        #pragma unroll
        for (int r = 0; r < 4; ++r) out[row * DD + 64 * r + lane] = yv[r];
    } else {
        // =============================== L wave ============================
        float a0l[8], a1l[8], Rl[4], xv[4], blv[4];
        #pragma unroll
        for (int r = 0; r < 4; ++r) {
            a0l[r]     = lv_b0[lane + 64 * r];
            a0l[4 + r] = lv_b0[255 + lane + 64 * r];
            a1l[r]     = lv_b1[lane + 64 * r];
            a1l[4 + r] = lv_b1[255 + lane + 64 * r];
            Rl[r] = 0.f;
            xv[r]  = x[row * DD + 64 * r + lane];
            blv[r] = lv_bo[64 * r + lane];
        }
        if (lane == 63) {
            a0l[3] = lv_b0[510]; a0l[7] = lv_b0[511];
            a1l[3] = lv_b1[510]; a1l[7] = lv_b1[511];
        }
        float4 e510A = a4[128 + lane], e510B = a4[192 + lane];
        float4 e511A = a4[384 + lane], e511B = a4[448 + lane];
        float4 wo510 = a4[576 + lane], wo511 = a4[704 + lane];

        LSet A, B;
        float ls_part = 0.f;

        {   // t = 0 scalar (R = 0): ls0/s0 owned by lane 0
            float ls0 = 0.5f * (Rl[0] + blv[0]);
            float s0  = __fdividef(1.f, __expf(ls0) + 1e-12f);
            ls_part += (lane == 0) ? ls0 : 0.f;
            if (lane == 0) exch[0][1] = s0;
        }

        // ---- step 0 (EX h=510) ----
        __syncthreads();
        {
            float2 ds0 = *(const float2*)&exch[0][0];
            float v0 = ds0.x * ds0.y;
            rdL(A, &buf[0][0], lane);
            rdL(B, &buf[1][0], lane);
            stepL<0, 1>(0, lane, v0, A, a0l, a1l, Rl, e510A, e510B, wo510);
            float lsn = 0.5f * (Rl[0] + blv[0]);
            float sn  = __fdividef(1.f, __expf(lsn) + 1e-12f);
            ls_part += (lane == 1) ? lsn : 0.f;
            if (lane == 1) exch[1][1] = sn;
            pinL(B);
        }
        // ---- step 1 (EX h=511) ----
        __syncthreads();
        {
            float2 ds1 = *(const float2*)&exch[1][0];
            float v1 = ds1.x * ds1.y;
            rdL(A, &buf[2][0], lane);
            stepL<0, 2>(1, lane, v1, B, a0l, a1l, Rl, e511A, e511B, wo511);
            float lsn = 0.5f * (Rl[0] + blv[0]);
            float sn  = __fdividef(1.f, __expf(lsn) + 1e-12f);
            ls_part += (lane == 2) ? lsn : 0.f;
            if (lane == 2) exch[0][1] = sn;
            pinL(A);
        }

#define LBODY(Q, tt, Qn, tn, SC, SN, PREF)                                    \
    {                                                                         \
        __syncthreads();                                                      \
        float2 ds_ = *(const float2*)&exch[(tt) & 1][0];                      \
        float v_ = ds_.x * ds_.y;                                             \
        if (PREF) rdL(SN, &buf[((tt) + 1) & 3][0], lane);                     \
        stepL<Q, 0>((tt) - 64 * (Q), lane, v_, SC, a0l, a1l, Rl, d4, d4, d4); \
        float lsn_ = 0.5f * (Rl[Qn] + blv[Qn]);                               \
        float sn_  = __fdividef(1.f, __expf(lsn_) + 1e-12f);                  \
        ls_part += (lane == (tn)) ? lsn_ : 0.f;                               \
        if (lane == (tn)) exch[((tt) + 1) & 1][1] = sn_;                      \
        if (PREF) pinL(SN);                                                   \
    }
        #pragma unroll 1
        for (int t = 2; t < 62; t += 2) {
            LBODY(0, t, 0, t + 1, A, B, 1)
            LBODY(0, t + 1, 0, t + 2, B, A, 1)
        }
        LBODY(0, 62, 0, 63, A, B, 1)
        LBODY(0, 63, 1, 0, B, A, 1)
        #pragma unroll 1
        for (int t = 64; t < 126; t += 2) {
            LBODY(1, t, 1, t - 63, A, B, 1)
            LBODY(1, t + 1, 1, t - 62, B, A, 1)
        }
        LBODY(1, 126, 1, 63, A, B, 1)
        LBODY(1, 127, 2, 0, B, A, 1)
        #pragma unroll 1
        for (int t = 128; t < 190; t += 2) {
            LBODY(2, t, 2, t - 127, A, B, 1)
            LBODY(2, t + 1, 2, t - 126, B, A, 1)
        }
        LBODY(2, 190, 2, 63, A, B, 1)
        LBODY(2, 191, 3, 0, B, A, 1)
        #pragma unroll 1
        for (int t = 192; t < 252; t += 2) {
            LBODY(3, t, 3, t - 191, A, B, 1)
            LBODY(3, t + 1, 3, t - 190, B, A, 1)
        }
        LBODY(3, 252, 3, 61, A, B, 1)
        LBODY(3, 253, 3, 62, B, A, 1)
        LBODY(3, 254, 3, 63, A, B, 0)
#undef LBODY

        // ---- t = 255: reduce ls and store ----
        __syncthreads();
        #pragma unroll
        for (int off = 32; off; off >>= 1)
            ls_part += __shfl_down(ls_part, off);
        if (lane == 0) out[BB * DD + row] = ls_part;
    }
}

extern "C" void kernel_launch(void* const* d_in, const int* in_sizes, int n_in,
                              void* d_out, int out_size, void* d_ws, size_t ws_size,
                              hipStream_t stream) {
    const float* x     = (const float*)d_in[0];
    const float* mu_W0 = (const float*)d_in[1];
    const float* mu_b0 = (const float*)d_in[2];
    const float* mu_W1 = (const float*)d_in[3];
    const float* mu_b1 = (const float*)d_in[4];
    const float* mu_Wo = (const float*)d_in[5];
    const float* mu_bo = (const float*)d_in[6];
    const float* lv_W0 = (const float*)d_in[7];
    const float* lv_b0 = (const float*)d_in[8];
    const float* lv_W1 = (const float*)d_in[9];
    const float* lv_b1 = (const float*)d_in[10];
    const float* lv_Wo = (const float*)d_in[11];
    const float* lv_bo = (const float*)d_in[12];

    float* tape = (float*)d_ws;   // 4 MiB

    prep<<<512, 256, 0, stream>>>(mu_W0, lv_W0, mu_W1, lv_W1, mu_Wo, lv_Wo, tape);
    made_main<<<BB, 192, 0, stream>>>(x, mu_b0, mu_b1, mu_bo,
                                      lv_b0, lv_b1, lv_bo, tape, (float*)d_out);
}